// Round 1
// 517.469 us; speedup vs baseline: 1.1688x; 1.1688x over previous
//
#include <hip/hip_runtime.h>

#define NTOKS 64
#define DIMS 256
#define NHEADS 8
#define NWIN 49
#define NBLK 3136

typedef __bf16 bf16x8 __attribute__((ext_vector_type(8)));
typedef __bf16 bf16x4 __attribute__((ext_vector_type(4)));
typedef float f32x4 __attribute__((ext_vector_type(4)));

__device__ __forceinline__ unsigned short f2bf(float f) {
    union { float f; unsigned u; } c; c.f = f;
    unsigned u = c.u;
    u += 0x7fffu + ((u >> 16) & 1u);   // RNE
    return (unsigned short)(u >> 16);
}

__device__ __forceinline__ bf16x8 pack8(f32x4 a, f32x4 b) {
    bf16x8 r;
    r[0] = (__bf16)a[0]; r[1] = (__bf16)a[1];
    r[2] = (__bf16)a[2]; r[3] = (__bf16)a[3];
    r[4] = (__bf16)b[0]; r[5] = (__bf16)b[1];
    r[6] = (__bf16)b[2]; r[7] = (__bf16)b[3];
    return r;
}

// ---------------- prep kernel ----------------
template<int NOUT>
__device__ __forceinline__ void ln_relu_fc(const float* v, const float* g, const float* bb,
                                           const float* fw, const float* fb, float* o) {
    float m = 0.f;
#pragma unroll
    for (int j = 0; j < 16; ++j) m += v[j];
    m *= (1.f / 16.f);
    float var = 0.f;
#pragma unroll
    for (int j = 0; j < 16; ++j) { float d = v[j] - m; var += d * d; }
    var *= (1.f / 16.f);
    float inv = rsqrtf(var + 1e-5f);
    float t[16];
#pragma unroll
    for (int j = 0; j < 16; ++j) {
        float xx = (v[j] - m) * inv * g[j] + bb[j];
        t[j] = xx > 0.f ? xx : 0.f;
    }
#pragma unroll
    for (int i = 0; i < NOUT; ++i) {
        float ss = fb[i];
#pragma unroll
        for (int j = 0; j < 16; ++j) ss += fw[i * 16 + j] * t[j];
        o[i] = ss;
    }
}

__global__ void prep_kernel(
    const float* __restrict__ qkv_w, const float* __restrict__ qkv_b,
    const float* __restrict__ proj_w, const float* __restrict__ mask,
    const float* __restrict__ pos_proj_w, const float* __restrict__ pos_proj_b,
    const float* __restrict__ ln1_g, const float* __restrict__ ln1_b,
    const float* __restrict__ fc1_w, const float* __restrict__ fc1_b,
    const float* __restrict__ ln2_g, const float* __restrict__ ln2_b,
    const float* __restrict__ fc2_w, const float* __restrict__ fc2_b,
    const float* __restrict__ ln3_g, const float* __restrict__ ln3_b,
    const float* __restrict__ fc3_w, const float* __restrict__ fc3_b,
    const float* __restrict__ biases, const int* __restrict__ rel_idx,
    unsigned short* __restrict__ qkvw_bf, unsigned short* __restrict__ projw_bf,
    float* __restrict__ qkvb_s, float* __restrict__ rpb_perm,
    float* __restrict__ mask_perm)
{
    const int tid = threadIdx.x;
    const int b = blockIdx.x;
    const float SC = 0.17677669529663687f;  // 32^-0.5

    if (b == 0) {
        __shared__ float p_sh[225 * 8];
        if (tid < 225) {
            float bx = biases[2 * tid], by = biases[2 * tid + 1];
            float v[16], u[16];
#pragma unroll
            for (int j = 0; j < 16; ++j)
                v[j] = pos_proj_w[2 * j] * bx + pos_proj_w[2 * j + 1] * by + pos_proj_b[j];
            ln_relu_fc<16>(v, ln1_g, ln1_b, fc1_w, fc1_b, u);
            ln_relu_fc<16>(u, ln2_g, ln2_b, fc2_w, fc2_b, v);
            ln_relu_fc<8>(v, ln3_g, ln3_b, fc3_w, fc3_b, u);
#pragma unroll
            for (int h = 0; h < 8; ++h) p_sh[tid * 8 + h] = u[h];
        }
        __syncthreads();
        // rpb_perm[(((h*4+kt)*4+quad)*64 + q)*4 + r] = p(rel_idx[q][kt*16+quad*4+r], h)
        for (int e = tid; e < 32768; e += 256) {
            int r = e & 3, q = (e >> 2) & 63, qd = (e >> 8) & 3, kt = (e >> 10) & 3, h = e >> 12;
            int key = kt * 16 + qd * 4 + r;
            rpb_perm[e] = p_sh[rel_idx[q * 64 + key] * 8 + h];
        }
    } else {
        const int t0 = (b - 1) * 256 + tid, NTH = 127 * 256;
        // bf16 swizzled weights: dst e = ((tile*8+kk)*64+lane)*8+j ; tile=16 rows of W
        for (int e = t0; e < 196608; e += NTH) {
            int j = e & 7, lane = (e >> 3) & 63, kk = (e >> 9) & 7, tile = e >> 12;
            int src = (tile * 16 + (lane & 15)) * 256 + kk * 32 + (lane >> 4) * 8 + j;
            float f = qkv_w[src];
            if (src < 65536) f *= SC;   // q rows pre-scaled
            qkvw_bf[e] = f2bf(f);
        }
        for (int e = t0; e < 65536; e += NTH) {
            int j = e & 7, lane = (e >> 3) & 63, kk = (e >> 9) & 7, tile = e >> 12;
            int src = (tile * 16 + (lane & 15)) * 256 + kk * 32 + (lane >> 4) * 8 + j;
            projw_bf[e] = f2bf(proj_w[src]);
        }
        // mask_perm[(((w*4+kt)*4+quad)*64 + q)*4 + r] = mask[w][q][kt*16+quad*4+r]
        for (int e = t0; e < 200704; e += NTH) {
            int r = e & 3, q = (e >> 2) & 63, qd = (e >> 8) & 3, kt = (e >> 10) & 3, w = e >> 12;
            int key = kt * 16 + qd * 4 + r;
            mask_perm[e] = mask[w * 4096 + q * 64 + key];
        }
        if (b == 1) {
            for (int e = tid; e < 768; e += 256)
                qkvb_s[e] = qkv_b[e] * (e < 256 ? SC : 1.f);
        }
    }
}

// ---------------- main fused kernel: one block (512 thr / 8 waves) per window ----------------
// wave h owns head h end-to-end. Q/K/V/P never touch LDS (register-resident via
// MFMA k-slot permutation: slot(quad,j) <-> d = 16*(j>>2)+4*quad+(j&3), identical
// on A and B operands so the reduction is unchanged).
// LDS: xs bf16 [64][256] XOR-swizzled (bytes [0,32768)) ; ctx bf16 [64][256] ([32768,65536)).
// Exactly 2 barriers. 64 KiB LDS + <=128 VGPR -> 2 blocks/CU.
__global__ __launch_bounds__(512, 4) void attn_kernel(
    const float* __restrict__ x,
    const unsigned short* __restrict__ qkvw, const float* __restrict__ qkvb,
    const unsigned short* __restrict__ projw, const float* __restrict__ projb,
    const float* __restrict__ rpb_perm, const float* __restrict__ mask_perm,
    float* __restrict__ out)
{
    __shared__ __align__(16) char ldsb[65536];
    const int tid  = threadIdx.x;
    const int h    = tid >> 6;          // wave id == head id
    const int lane = tid & 63;
    const int quad = lane >> 4;
    const int l16  = lane & 15;
    const int sw   = (l16 & 7) << 4;    // XOR swizzle for rows 16t+l16
    const int blk  = blockIdx.x;
    const int w    = blk % NWIN;
    const f32x4 FZ = {0.f, 0.f, 0.f, 0.f};

    // ---- stage x (fp32 -> bf16, XOR-swizzled 512B rows) ----
    {
        const float4* xv = (const float4*)(x + (size_t)blk * (NTOKS * DIMS));
#pragma unroll
        for (int it = 0; it < 8; ++it) {
            int i = tid + it * 512;
            float4 f = xv[i];
            int row = i >> 6;
            int colb = (i & 63) << 3;
            bf16x4 hv;
            hv[0] = (__bf16)f.x; hv[1] = (__bf16)f.y;
            hv[2] = (__bf16)f.z; hv[3] = (__bf16)f.w;
            *(bf16x4*)(ldsb + row * 512 + (colb ^ ((row & 7) << 4))) = hv;
        }
    }
    __syncthreads();

    const int xbase = l16 * 512;
#define XFRAG(t, kk) (*(const bf16x8*)(ldsb + (t) * 8192 + xbase + ((((kk) * 64) + quad * 16) ^ sw)))
#define CFRAG(t, kk) (*(const bf16x8*)(ldsb + 32768 + (t) * 8192 + xbase + ((((kk) * 64) + quad * 16) ^ sw)))

    // ---- pass 1: Q^T, K^T for this head; D[m=d][n=token] ----
    f32x4 qa[2][4], ka[2][4];
#pragma unroll
    for (int mt = 0; mt < 2; ++mt)
#pragma unroll
        for (int nt = 0; nt < 4; ++nt) { qa[mt][nt] = FZ; ka[mt][nt] = FZ; }
    {
        const unsigned short* pQ = qkvw + (size_t)((2 * h) * 8) * 512 + lane * 8;
        const unsigned short* pK = qkvw + (size_t)((16 + 2 * h) * 8) * 512 + lane * 8;
#pragma unroll 2
        for (int kk = 0; kk < 8; ++kk) {
            bf16x8 xb[4];
#pragma unroll
            for (int nt = 0; nt < 4; ++nt) xb[nt] = XFRAG(nt, kk);
            bf16x8 wq[2], wk[2];
#pragma unroll
            for (int mt = 0; mt < 2; ++mt) {
                wq[mt] = *(const bf16x8*)&pQ[(mt * 8 + kk) * 512];
                wk[mt] = *(const bf16x8*)&pK[(mt * 8 + kk) * 512];
            }
#pragma unroll
            for (int mt = 0; mt < 2; ++mt)
#pragma unroll
                for (int nt = 0; nt < 4; ++nt) {
                    qa[mt][nt] = __builtin_amdgcn_mfma_f32_16x16x32_bf16(wq[mt], xb[nt], qa[mt][nt], 0, 0, 0);
                    ka[mt][nt] = __builtin_amdgcn_mfma_f32_16x16x32_bf16(wk[mt], xb[nt], ka[mt][nt], 0, 0, 0);
                }
        }
    }
    // biases (q bias pre-scaled in prep)
#pragma unroll
    for (int mt = 0; mt < 2; ++mt) {
        f32x4 qb = *(const f32x4*)&qkvb[h * 32 + mt * 16 + quad * 4];
        f32x4 kb = *(const f32x4*)&qkvb[256 + h * 32 + mt * 16 + quad * 4];
#pragma unroll
        for (int nt = 0; nt < 4; ++nt) {
#pragma unroll
            for (int r = 0; r < 4; ++r) { qa[mt][nt][r] += qb[r]; ka[mt][nt][r] += kb[r]; }
        }
    }
    // fragments for S: slot(quad,j) -> d = 16*(j>>2)+4*quad+(j&3) == accum (mt=j>>2, r=j&3)
    bf16x8 Qp[4], Kp[4];
#pragma unroll
    for (int t = 0; t < 4; ++t) {
        Qp[t] = pack8(qa[0][t], qa[1][t]);
        Kp[t] = pack8(ka[0][t], ka[1][t]);
    }

    // ---- S = K·Q^T ; D[m=key][n=query]; C-init = rpb + mask ----
    f32x4 s[4][4];      // s[kt][qt]: key = kt*16+quad*4+r, query = qt*16+l16
    {
        const f32x4* rp4 = (const f32x4*)rpb_perm + ((h * 16 + quad) * 64 + l16);
        const f32x4* mp4 = (const f32x4*)mask_perm + ((w * 16 + quad) * 64 + l16);
#pragma unroll
        for (int kt = 0; kt < 4; ++kt)
#pragma unroll
            for (int qt = 0; qt < 4; ++qt) {
                f32x4 rv = rp4[kt * 256 + qt * 16];
                f32x4 mv = mp4[kt * 256 + qt * 16];
                s[kt][qt] = rv + mv;
            }
#pragma unroll
        for (int kt = 0; kt < 4; ++kt)
#pragma unroll
            for (int qt = 0; qt < 4; ++qt)
                s[kt][qt] = __builtin_amdgcn_mfma_f32_16x16x32_bf16(Kp[kt], Qp[qt], s[kt][qt], 0, 0, 0);
    }

    // ---- softmax over keys: 16 in-lane + cross-quad shfl ----
#pragma unroll
    for (int qt = 0; qt < 4; ++qt) {
        float mx = s[0][qt][0];
#pragma unroll
        for (int kt = 0; kt < 4; ++kt)
#pragma unroll
            for (int r = 0; r < 4; ++r) mx = fmaxf(mx, s[kt][qt][r]);
        mx = fmaxf(mx, __shfl_xor(mx, 16));
        mx = fmaxf(mx, __shfl_xor(mx, 32));
        float sum = 0.f;
#pragma unroll
        for (int kt = 0; kt < 4; ++kt)
#pragma unroll
            for (int r = 0; r < 4; ++r) {
                float e = __expf(s[kt][qt][r] - mx);
                s[kt][qt][r] = e; sum += e;
            }
        sum += __shfl_xor(sum, 16);
        sum += __shfl_xor(sum, 32);
        float inv = 1.0f / sum;
#pragma unroll
        for (int kt = 0; kt < 4; ++kt)
#pragma unroll
            for (int r = 0; r < 4; ++r) s[kt][qt][r] *= inv;
    }
    // P fragments: slot(quad,j,ks) -> tok = 32ks+16*(j>>2)+4*quad+(j&3) == s[2ks+(j>>2)][qt][j&3]
    bf16x8 Pp[4][2];
#pragma unroll
    for (int qt = 0; qt < 4; ++qt)
#pragma unroll
        for (int ks = 0; ks < 2; ++ks)
            Pp[qt][ks] = pack8(s[2 * ks][qt], s[2 * ks + 1][qt]);

    // ---- pass 2: V ; D[m=token][n=d] ----
    f32x4 va[4][2];
#pragma unroll
    for (int mt = 0; mt < 4; ++mt)
#pragma unroll
        for (int nt = 0; nt < 2; ++nt) va[mt][nt] = FZ;
    {
        const unsigned short* pV = qkvw + (size_t)((32 + 2 * h) * 8) * 512 + lane * 8;
#pragma unroll 2
        for (int kk = 0; kk < 8; ++kk) {
            bf16x8 xa[4];
#pragma unroll
            for (int mt = 0; mt < 4; ++mt) xa[mt] = XFRAG(mt, kk);
            bf16x8 wv[2];
#pragma unroll
            for (int nt = 0; nt < 2; ++nt) wv[nt] = *(const bf16x8*)&pV[(nt * 8 + kk) * 512];
#pragma unroll
            for (int mt = 0; mt < 4; ++mt)
#pragma unroll
                for (int nt = 0; nt < 2; ++nt)
                    va[mt][nt] = __builtin_amdgcn_mfma_f32_16x16x32_bf16(xa[mt], wv[nt], va[mt][nt], 0, 0, 0);
        }
        float vb0 = qkvb[512 + h * 32 + l16];
        float vb1 = qkvb[512 + h * 32 + 16 + l16];
#pragma unroll
        for (int mt = 0; mt < 4; ++mt)
#pragma unroll
            for (int r = 0; r < 4; ++r) { va[mt][0][r] += vb0; va[mt][1][r] += vb1; }
    }
    bf16x8 Vp[2][2];    // [ks][nt]
#pragma unroll
    for (int ks = 0; ks < 2; ++ks)
#pragma unroll
        for (int nt = 0; nt < 2; ++nt)
            Vp[ks][nt] = pack8(va[2 * ks][nt], va[2 * ks + 1][nt]);

    // ---- PV: O[q][d] ----
    f32x4 o[4][2];
#pragma unroll
    for (int qt = 0; qt < 4; ++qt)
#pragma unroll
        for (int nt = 0; nt < 2; ++nt) {
            f32x4 a0 = __builtin_amdgcn_mfma_f32_16x16x32_bf16(Pp[qt][0], Vp[0][nt], FZ, 0, 0, 0);
            o[qt][nt] = __builtin_amdgcn_mfma_f32_16x16x32_bf16(Pp[qt][1], Vp[1][nt], a0, 0, 0, 0);
        }

    // ---- ctx write (bf16, swizzled) ----
    {
        const int chb = 2 * (h * 32 + l16);
#pragma unroll
        for (int qt = 0; qt < 4; ++qt)
#pragma unroll
            for (int r = 0; r < 4; ++r) {
                int row = qt * 16 + quad * 4 + r;
                int rsw = (row & 7) << 4;
#pragma unroll
                for (int nt = 0; nt < 2; ++nt)
                    *(__bf16*)(ldsb + 32768 + row * 512 + ((chb + 32 * nt) ^ rsw)) = (__bf16)o[qt][nt][r];
            }
    }
    __syncthreads();

    // ---- proj: out = ctx @ Wproj^T + b ; wave covers 32 output cols ----
    {
        f32x4 c_[4][2];
#pragma unroll
        for (int mt = 0; mt < 4; ++mt)
#pragma unroll
            for (int nt = 0; nt < 2; ++nt) c_[mt][nt] = FZ;
        const unsigned short* pP = projw + (size_t)((2 * h) * 8) * 512 + lane * 8;
#pragma unroll 2
        for (int kk = 0; kk < 8; ++kk) {
            bf16x8 a[4];
#pragma unroll
            for (int mt = 0; mt < 4; ++mt) a[mt] = CFRAG(mt, kk);
            bf16x8 bwp[2];
#pragma unroll
            for (int nt = 0; nt < 2; ++nt) bwp[nt] = *(const bf16x8*)&pP[(nt * 8 + kk) * 512];
#pragma unroll
            for (int mt = 0; mt < 4; ++mt)
#pragma unroll
                for (int nt = 0; nt < 2; ++nt)
                    c_[mt][nt] = __builtin_amdgcn_mfma_f32_16x16x32_bf16(a[mt], bwp[nt], c_[mt][nt], 0, 0, 0);
        }
        float pb0 = projb[h * 32 + l16];
        float pb1 = projb[h * 32 + 16 + l16];
        float* ob = out + (size_t)blk * (NTOKS * DIMS) + h * 32 + l16;
#pragma unroll
        for (int mt = 0; mt < 4; ++mt)
#pragma unroll
            for (int r = 0; r < 4; ++r) {
                int row = mt * 16 + quad * 4 + r;
                ob[row * 256]      = c_[mt][0][r] + pb0;
                ob[row * 256 + 16] = c_[mt][1][r] + pb1;
            }
    }
#undef XFRAG
#undef CFRAG
}

extern "C" void kernel_launch(void* const* d_in, const int* in_sizes, int n_in,
                              void* d_out, int out_size, void* d_ws, size_t ws_size,
                              hipStream_t stream) {
    const float* x          = (const float*)d_in[0];
    const float* mask       = (const float*)d_in[1];
    const float* qkv_w      = (const float*)d_in[2];
    const float* qkv_b      = (const float*)d_in[3];
    const float* proj_w     = (const float*)d_in[4];
    const float* proj_b     = (const float*)d_in[5];
    const float* pos_proj_w = (const float*)d_in[6];
    const float* pos_proj_b = (const float*)d_in[7];
    const float* ln1_g      = (const float*)d_in[8];
    const float* ln1_b      = (const float*)d_in[9];
    const float* fc1_w      = (const float*)d_in[10];
    const float* fc1_b      = (const float*)d_in[11];
    const float* ln2_g      = (const float*)d_in[12];
    const float* ln2_b      = (const float*)d_in[13];
    const float* fc2_w      = (const float*)d_in[14];
    const float* fc2_b      = (const float*)d_in[15];
    const float* ln3_g      = (const float*)d_in[16];
    const float* ln3_b      = (const float*)d_in[17];
    const float* fc3_w      = (const float*)d_in[18];
    const float* fc3_b      = (const float*)d_in[19];
    const float* biases     = (const float*)d_in[20];
    const int*   rel_idx    = (const int*)d_in[21];
    float* out = (float*)d_out;

    char* ws = (char*)d_ws;
    unsigned short* qkvw_bf  = (unsigned short*)(ws);            // 393216 B
    unsigned short* projw_bf = (unsigned short*)(ws + 393216);   // 131072 B
    float* qkvb_s    = (float*)(ws + 524288);                    //   3072 B
    float* rpb_perm  = (float*)(ws + 528384);                    // 131072 B
    float* mask_perm = (float*)(ws + 659456);                    // 802816 B -> end 1462272

    prep_kernel<<<dim3(128), dim3(256), 0, stream>>>(
        qkv_w, qkv_b, proj_w, mask, pos_proj_w, pos_proj_b,
        ln1_g, ln1_b, fc1_w, fc1_b, ln2_g, ln2_b, fc2_w, fc2_b,
        ln3_g, ln3_b, fc3_w, fc3_b, biases, rel_idx,
        qkvw_bf, projw_bf, qkvb_s, rpb_perm, mask_perm);

    attn_kernel<<<dim3(NBLK), dim3(512), 0, stream>>>(
        x, qkvw_bf, qkvb_s, projw_bf, proj_b, rpb_perm, mask_perm, out);
}